// Round 1
// baseline (91.327 us; speedup 1.0000x reference)
//
#include <hip/hip_runtime.h>
#include <hip/hip_bf16.h>

#define B_  8
#define CI_ 32
#define CO_ 64
#define F_  4
#define H_  64
#define W_  64

// Kernel 1: one block per (b,i). Computes
//   iv[b,i]   = dx^2 * sum_{h,w} wgt * v[b,i,h,w]
//   T[b,i,d]  = dx^2 * sum_{h,w} wgt * vc[h,w,d] * v[b,i,h,w]
// wgt = trapezoid weights (0.5 at h/w boundaries).
__global__ __launch_bounds__(256) void k_reduce(
    const float* __restrict__ v, const float* __restrict__ vc,
    float* __restrict__ iv, float* __restrict__ T) {
  const int bi = blockIdx.x;                 // 0 .. B*CI-1
  const int tid = threadIdx.x;               // 256 threads
  const float* vp = v + (size_t)bi * (H_ * W_);

  float s0 = 0.f, s1 = 0.f, s2 = 0.f;
  for (int p = tid; p < H_ * W_; p += 256) {
    int h = p >> 6;
    int w = p & 63;
    float wgt = ((h == 0 || h == H_ - 1) ? 0.5f : 1.0f) *
                ((w == 0 || w == W_ - 1) ? 0.5f : 1.0f);
    float val = vp[p] * wgt;
    float cx = vc[2 * p];
    float cy = vc[2 * p + 1];
    s0 += val;
    s1 += val * cx;
    s2 += val * cy;
  }

  // wave (64-lane) reduce, then cross-wave via LDS
  for (int off = 32; off > 0; off >>= 1) {
    s0 += __shfl_down(s0, off, 64);
    s1 += __shfl_down(s1, off, 64);
    s2 += __shfl_down(s2, off, 64);
  }
  __shared__ float red[4][3];
  int wave = tid >> 6;
  int lane = tid & 63;
  if (lane == 0) {
    red[wave][0] = s0; red[wave][1] = s1; red[wave][2] = s2;
  }
  __syncthreads();
  if (tid == 0) {
    float t0 = red[0][0] + red[1][0] + red[2][0] + red[3][0];
    float t1 = red[0][1] + red[1][1] + red[2][1] + red[3][1];
    float t2 = red[0][2] + red[1][2] + red[2][2] + red[3][2];
    float dx = vc[2] - vc[0];        // v_coords[0,1,0] - v_coords[0,0,0]
    float sc = dx * dx;
    iv[bi]        = t0 * sc;
    T[2 * bi]     = t1 * sc;
    T[2 * bi + 1] = t2 * sc;
  }
}

// Kernel 2: one thread per (b,o). Computes
//   Sx[b,o,d] = sum_{f,i} Wx[f,o,i,d] * iv[b,i]
//   C[b,o]    = sum_{f,i,d} Wy[f,o,i,d] * T[b,i,d]
// Packed as SxC[(b*CO+o)*3 + {0,1,2}].
__global__ __launch_bounds__(256) void k_combine(
    const float* __restrict__ Wx, const float* __restrict__ Wy,
    const float* __restrict__ iv, const float* __restrict__ T,
    float* __restrict__ SxC) {
  int t = blockIdx.x * blockDim.x + threadIdx.x;
  if (t >= B_ * CO_) return;
  int b = t / CO_;
  int o = t - b * CO_;

  float sx0 = 0.f, sx1 = 0.f, c = 0.f;
  for (int i = 0; i < CI_; ++i) {
    float ivbi = iv[b * CI_ + i];
    float t0 = T[(b * CI_ + i) * 2];
    float t1 = T[(b * CI_ + i) * 2 + 1];
#pragma unroll
    for (int f = 0; f < F_; ++f) {
      int base = ((f * CO_ + o) * CI_ + i) * 2;
      float wx0 = Wx[base], wx1 = Wx[base + 1];
      float wy0 = Wy[base], wy1 = Wy[base + 1];
      sx0 += wx0 * ivbi;
      sx1 += wx1 * ivbi;
      c   += wy0 * t0 + wy1 * t1;
    }
  }
  SxC[t * 3]     = sx0;
  SxC[t * 3 + 1] = sx1;
  SxC[t * 3 + 2] = c;
}

// Kernel 3: out[b,o,h,w] = tc[h,w,0]*Sx0 + tc[h,w,1]*Sx1 + C, float4-vectorized
// along w (4 pixels / thread).
__global__ __launch_bounds__(256) void k_out(
    const float* __restrict__ tc, const float* __restrict__ SxC,
    float* __restrict__ out) {
  int q = blockIdx.x * blockDim.x + threadIdx.x;   // 0 .. B*CO*H*W/4 - 1
  int bo = q >> 10;                                // 1024 float4 per (b,o)
  int p4 = q & 1023;
  int h  = p4 >> 4;                                // W/4 = 16
  int w4 = p4 & 15;

  float sx0 = SxC[bo * 3];
  float sx1 = SxC[bo * 3 + 1];
  float c   = SxC[bo * 3 + 2];

  const float4* tcp = (const float4*)(tc + (size_t)(h * W_ + w4 * 4) * 2);
  float4 t0 = tcp[0];   // gx0, gy0, gx1, gy1
  float4 t1 = tcp[1];   // gx2, gy2, gx3, gy3

  float4 r;
  r.x = t0.x * sx0 + t0.y * sx1 + c;
  r.y = t0.z * sx0 + t0.w * sx1 + c;
  r.z = t1.x * sx0 + t1.y * sx1 + c;
  r.w = t1.z * sx0 + t1.w * sx1 + c;

  ((float4*)out)[q] = r;
}

extern "C" void kernel_launch(void* const* d_in, const int* in_sizes, int n_in,
                              void* d_out, int out_size, void* d_ws, size_t ws_size,
                              hipStream_t stream) {
  const float* v  = (const float*)d_in[0];   // [B,CI,H,W]
  const float* vc = (const float*)d_in[1];   // [H,W,2]
  const float* tc = (const float*)d_in[2];   // [H,W,2]
  const float* Wx = (const float*)d_in[3];   // [F,CO,CI,2]
  const float* Wy = (const float*)d_in[4];   // [F,CO,CI,2]
  float* out = (float*)d_out;                // [B,CO,H,W]

  // workspace layout (floats): iv[256] | T[512] | SxC[1536]
  float* iv  = (float*)d_ws;
  float* T   = iv + B_ * CI_;
  float* SxC = T + B_ * CI_ * 2;

  k_reduce<<<B_ * CI_, 256, 0, stream>>>(v, vc, iv, T);
  k_combine<<<(B_ * CO_ + 255) / 256, 256, 0, stream>>>(Wx, Wy, iv, T, SxC);
  int n4 = B_ * CO_ * H_ * W_ / 4;           // 524288 threads
  k_out<<<n4 / 256, 256, 0, stream>>>(tc, SxC, out);
}

// Round 2
// 71.151 us; speedup vs baseline: 1.2836x; 1.2836x over previous
//
#include <hip/hip_runtime.h>
#include <hip/hip_bf16.h>

#define B_  8
#define CI_ 32
#define CO_ 64
#define F_  4
#define H_  64
#define W_  64

// Kernel 1: one block per (b,i). Computes
//   iv[b,i]   = dx^2 * sum_{h,w} wgt * v[b,i,h,w]
//   T[b,i,d]  = dx^2 * sum_{h,w} wgt * vc[h,w,d] * v[b,i,h,w]
// wgt = trapezoid weights (0.5 at h/w boundaries).
__global__ __launch_bounds__(256) void k_reduce(
    const float* __restrict__ v, const float* __restrict__ vc,
    float* __restrict__ iv, float* __restrict__ T) {
  const int bi = blockIdx.x;                 // 0 .. B*CI-1
  const int tid = threadIdx.x;               // 256 threads
  const float* vp = v + (size_t)bi * (H_ * W_);

  float s0 = 0.f, s1 = 0.f, s2 = 0.f;
  for (int p = tid; p < H_ * W_; p += 256) {
    int h = p >> 6;
    int w = p & 63;
    float wgt = ((h == 0 || h == H_ - 1) ? 0.5f : 1.0f) *
                ((w == 0 || w == W_ - 1) ? 0.5f : 1.0f);
    float val = vp[p] * wgt;
    float cx = vc[2 * p];
    float cy = vc[2 * p + 1];
    s0 += val;
    s1 += val * cx;
    s2 += val * cy;
  }

  for (int off = 32; off > 0; off >>= 1) {
    s0 += __shfl_down(s0, off, 64);
    s1 += __shfl_down(s1, off, 64);
    s2 += __shfl_down(s2, off, 64);
  }
  __shared__ float red[4][3];
  int wave = tid >> 6;
  int lane = tid & 63;
  if (lane == 0) {
    red[wave][0] = s0; red[wave][1] = s1; red[wave][2] = s2;
  }
  __syncthreads();
  if (tid == 0) {
    float t0 = red[0][0] + red[1][0] + red[2][0] + red[3][0];
    float t1 = red[0][1] + red[1][1] + red[2][1] + red[3][1];
    float t2 = red[0][2] + red[1][2] + red[2][2] + red[3][2];
    float dx = vc[2] - vc[0];        // v_coords[0,1,0] - v_coords[0,0,0]
    float sc = dx * dx;
    iv[bi]        = t0 * sc;
    T[2 * bi]     = t1 * sc;
    T[2 * bi + 1] = t2 * sc;
  }
}

// Kernel 2 (fused combine + output): 4 blocks per (b,o). Each block first
// computes the 3 affine coefficients
//   Sx0 = sum_{f,i} Wx[f,o,i,0]*iv[b,i]
//   Sx1 = sum_{f,i} Wx[f,o,i,1]*iv[b,i]
//   C   = sum_{f,i,d} Wy[f,o,i,d]*T[b,i,d]
// using 128 threads (one (i,f) term each; Wx/Wy slices are L2-hot, ~2KB),
// then writes its quarter of the 64x64 plane as float4:
//   out[b,o,h,w] = tc[h,w,0]*Sx0 + tc[h,w,1]*Sx1 + C
__global__ __launch_bounds__(256) void k_out_fused(
    const float* __restrict__ tc, const float* __restrict__ Wx,
    const float* __restrict__ Wy, const float* __restrict__ iv,
    const float* __restrict__ T, float* __restrict__ out) {
  const int blk = blockIdx.x;        // 0 .. B*CO*4 - 1
  const int tid = threadIdx.x;       // 256
  const int bo  = blk >> 2;          // (b*CO + o)
  const int b   = bo >> 6;           // CO = 64
  const int o   = bo & 63;

  float sx0 = 0.f, sx1 = 0.f, c = 0.f;
  if (tid < CI_ * F_) {              // 128 active terms
    int i = tid & (CI_ - 1);
    int f = tid >> 5;
    float ivbi = iv[b * CI_ + i];
    float t0 = T[(b * CI_ + i) * 2];
    float t1 = T[(b * CI_ + i) * 2 + 1];
    int base = ((f * CO_ + o) * CI_ + i) * 2;
    float2 wx = *(const float2*)(Wx + base);
    float2 wy = *(const float2*)(Wy + base);
    sx0 = wx.x * ivbi;
    sx1 = wx.y * ivbi;
    c   = wy.x * t0 + wy.y * t1;
  }
  // reduce over waves 0,1 (lanes of waves 2,3 hold zeros)
  for (int off = 32; off > 0; off >>= 1) {
    sx0 += __shfl_down(sx0, off, 64);
    sx1 += __shfl_down(sx1, off, 64);
    c   += __shfl_down(c,   off, 64);
  }
  __shared__ float red[2][3];
  __shared__ float bc[3];
  int wave = tid >> 6;
  int lane = tid & 63;
  if (wave < 2 && lane == 0) {
    red[wave][0] = sx0; red[wave][1] = sx1; red[wave][2] = c;
  }
  __syncthreads();
  if (tid == 0) {
    bc[0] = red[0][0] + red[1][0];
    bc[1] = red[0][1] + red[1][1];
    bc[2] = red[0][2] + red[1][2];
  }
  __syncthreads();
  const float SX0 = bc[0], SX1 = bc[1], C = bc[2];

  // this block's quarter of the plane: 256 float4 (= 1024 pixels)
  int p4 = (blk & 3) * 256 + tid;    // 0..1023 float4-index within (b,o)
  int h  = p4 >> 4;                  // W/4 = 16 float4 per row
  int w4 = p4 & 15;

  const float4* tcp = (const float4*)(tc + (size_t)(h * W_ + w4 * 4) * 2);
  float4 t0v = tcp[0];   // gx0, gy0, gx1, gy1
  float4 t1v = tcp[1];   // gx2, gy2, gx3, gy3

  float4 r;
  r.x = t0v.x * SX0 + t0v.y * SX1 + C;
  r.y = t0v.z * SX0 + t0v.w * SX1 + C;
  r.z = t1v.x * SX0 + t1v.y * SX1 + C;
  r.w = t1v.z * SX0 + t1v.w * SX1 + C;

  ((float4*)out)[(size_t)bo * 1024 + p4] = r;
}

extern "C" void kernel_launch(void* const* d_in, const int* in_sizes, int n_in,
                              void* d_out, int out_size, void* d_ws, size_t ws_size,
                              hipStream_t stream) {
  const float* v  = (const float*)d_in[0];   // [B,CI,H,W]
  const float* vc = (const float*)d_in[1];   // [H,W,2]
  const float* tc = (const float*)d_in[2];   // [H,W,2]
  const float* Wx = (const float*)d_in[3];   // [F,CO,CI,2]
  const float* Wy = (const float*)d_in[4];   // [F,CO,CI,2]
  float* out = (float*)d_out;                // [B,CO,H,W]

  // workspace layout (floats): iv[256] | T[512]
  float* iv = (float*)d_ws;
  float* T  = iv + B_ * CI_;

  k_reduce<<<B_ * CI_, 256, 0, stream>>>(v, vc, iv, T);
  k_out_fused<<<B_ * CO_ * 4, 256, 0, stream>>>(tc, Wx, Wy, iv, T, out);
}